// Round 3
// baseline (150.504 us; speedup 1.0000x reference)
//
#include <hip/hip_runtime.h>
#include <cstdint>
#include <cstddef>

#define CIN     16
#define T_DIM   31
#define HW_     16384            // 128*128
#define CH_STRIDE 507904         // 31*128*128
#define TILE_H  8
#define TILE_W  16
#define SH      10
#define SW      18
#define SPOS    (SH * SW)        // 180 positions per slice
#define SLICE_SH (SPOS * CIN)    // 2880 shorts per slice

typedef short bf16x8 __attribute__((ext_vector_type(8)));
typedef float f32x16 __attribute__((ext_vector_type(16)));

__device__ __forceinline__ unsigned bf16_bits(float x) {
  unsigned u = __builtin_bit_cast(unsigned, x);
  u += 0x7FFFu + ((u >> 16) & 1u);   // RTNE
  return u >> 16;
}

__global__ __launch_bounds__(256, 2)
void qrnn3d_mfma2(const float* __restrict__ in, const float* __restrict__ Wg,
                  const float* __restrict__ bg, float* __restrict__ out) {
  // 4-slot ring of bf16 slices, [pos 0..179][ci 0..15], 23 KiB total
  __shared__ short xs[4][SLICE_SH];

  const int tid  = threadIdx.x;
  const int bid  = blockIdx.x;
  const int b    = bid >> 7;           // 4 batches x 128 tiles
  const int tile = bid & 127;
  const int h0   = (tile >> 3) * TILE_H;   // 16 h-tiles
  const int w0   = (tile & 7) * TILE_W;    // 8 w-tiles

  const int lane = tid & 63;
  const int wid  = tid >> 6;           // wave 0..3
  const int col  = lane & 31;          // MFMA N column
  const int half = lane >> 5;          // K half (ci 0-7 / 8-15)

  // ---- weights -> 27 A-frags in registers (one-time, L2-cached) ----
  bf16x8 wfrag[27];
#pragma unroll
  for (int tau = 0; tau < 27; ++tau) {
    bf16x8 f;
#pragma unroll
    for (int j = 0; j < 8; ++j)
      f[j] = (short)bf16_bits(Wg[col * 432 + (half * 8 + j) * 27 + tau]);
    wfrag[tau] = f;
  }

  // ---- per-lane bias / output-channel offsets ----
  float bz[8], bf_[8];
  int   ocoff[8];
#pragma unroll
  for (int r = 0; r < 8; ++r) {
    int oc   = (r & 3) + 8 * (r >> 2) + 4 * half;   // 0..15
    bz[r]    = bg[oc];
    bf_[r]   = bg[oc + 16];
    ocoff[r] = oc * CH_STRIDE;
  }

  // ---- staging precompute (t-invariant): thread -> (ci-quad, position) ----
  // p = j*64 + c4*16 + q : 16-lane position runs (64B global segments),
  // ds_write_b64 per thread -> bank-disjoint across ci-quads (conflict-free).
  const float* gptr[3];
  int  lsoff[3];
  bool stv[3], ldv[3];
#pragma unroll
  for (int i = 0; i < 3; ++i) {
    int p   = tid + i * 256;           // [0,768)
    int j   = p >> 6;
    int c4  = (p >> 4) & 3;
    int q   = p & 15;
    int pos = j * 16 + q;              // [0,192)
    stv[i]  = (pos < SPOS);
    int hh  = pos / 18;
    int ww  = pos - hh * 18;
    int gh  = h0 + hh - 1, gw = w0 + ww - 1;
    ldv[i]  = stv[i] && ((unsigned)gh < 128u) && ((unsigned)gw < 128u);
    int sp_off = ldv[i] ? (gh * 128 + gw) : 0;
    gptr[i] = in + (size_t)(b * CIN + c4 * 4) * CH_STRIDE + sp_off;
    lsoff[i] = pos * CIN + c4 * 4;     // shorts
  }

  float vv[3][4];
  auto stage_load = [&](int tz) {
    const bool tzok = (tz < T_DIM);
    const int  toff = tz * HW_;
#pragma unroll
    for (int i = 0; i < 3; ++i) {
      const bool ok = ldv[i] && tzok;
#pragma unroll
      for (int k = 0; k < 4; ++k)
        vv[i][k] = ok ? gptr[i][toff + k * CH_STRIDE] : 0.0f;
    }
  };
  auto stage_store = [&](short* dst) {
#pragma unroll
    for (int i = 0; i < 3; ++i) {
      if (stv[i]) {
        unsigned u0 = (bf16_bits(vv[i][0]) & 0xFFFFu) | (bf16_bits(vv[i][1]) << 16);
        unsigned u1 = (bf16_bits(vv[i][2]) & 0xFFFFu) | (bf16_bits(vv[i][3]) << 16);
        uint2 u = make_uint2(u0, u1);
        *reinterpret_cast<uint2*>(dst + lsoff[i]) = u;   // ds_write_b64
      }
    }
  };

  // ---- prologue: slot3 = zeros (slice -1), slices 0,1 staged, slice 2 in flight
  for (int i = tid; i < SLICE_SH / 2; i += 256)
    reinterpret_cast<unsigned*>(&xs[3][0])[i] = 0u;
  stage_load(0); stage_store(&xs[0][0]);
  stage_load(1); stage_store(&xs[1][0]);
  stage_load(2);
  __syncthreads();

  // ---- per-lane compute geometry ----
  const int srow  = 2 * wid + (col >> 4);       // tile row 0..7
  const int colw  = col & 15;                   // tile col 0..15
  const int lbase = (srow * SW + colw) * CIN + half * 8;   // shorts (halo: slice row = srow+kh)
  const size_t obase = (size_t)b * CIN * CH_STRIDE + (size_t)(h0 + srow) * 128 + (w0 + colw);

  float hst[8];
#pragma unroll
  for (int r = 0; r < 8; ++r) hst[r] = 0.0f;

  int tOff = 0;
#pragma unroll 1
  for (int t = 0; t < T_DIM; ++t) {
    // store slice t+2 (regs loaded last iter; slot (t+2)&3 is not read this step)
    if (t <= 29) stage_store(&xs[0][0] + ((t + 2) & 3) * SLICE_SH);
    // issue loads for slice t+3 (zeros if past the end)
    if (t <= 28) stage_load(t + 3);

    const short* sA = &xs[0][0] + ((t + 3) & 3) * SLICE_SH;  // slice t-1
    const short* sB = &xs[0][0] + ((t    ) & 3) * SLICE_SH;  // slice t
    const short* sC = &xs[0][0] + ((t + 1) & 3) * SLICE_SH;  // slice t+1

    f32x16 acc0, acc1;
#pragma unroll
    for (int i = 0; i < 16; ++i) { acc0[i] = 0.0f; acc1[i] = 0.0f; }

#pragma unroll
    for (int kd = 0; kd < 3; ++kd) {
      const short* sp = (kd == 0) ? sA : (kd == 1) ? sB : sC;
#pragma unroll
      for (int kh = 0; kh < 3; ++kh) {
#pragma unroll
        for (int kw = 0; kw < 3; ++kw) {
          const int tau = kd * 9 + kh * 3 + kw;
          bf16x8 xb = *reinterpret_cast<const bf16x8*>(sp + lbase + (kh * SW + kw) * CIN);
          if (tau & 1)
            acc1 = __builtin_amdgcn_mfma_f32_32x32x16_bf16(wfrag[tau], xb, acc1, 0, 0, 0);
          else
            acc0 = __builtin_amdgcn_mfma_f32_32x32x16_bf16(wfrag[tau], xb, acc0, 0, 0, 0);
        }
      }
    }

    // activations + fo-pool + stores (register-only recurrence)
#pragma unroll
    for (int r = 0; r < 8; ++r) {
      float zg = acc0[r]     + acc1[r]     + bz[r];
      float fg = acc0[r + 8] + acc1[r + 8] + bf_[r];
      float z  = 1.0f - 2.0f / (__expf(2.0f * zg) + 1.0f);
      float f  = 1.0f / (1.0f + __expf(-fg));
      float h  = f * hst[r] + (1.0f - f) * z;
      hst[r]   = h;
      out[obase + ocoff[r] + tOff] = h;
    }
    tOff += HW_;

    if (t < 30) __syncthreads();
  }
}

extern "C" void kernel_launch(void* const* d_in, const int* in_sizes, int n_in,
                              void* d_out, int out_size, void* d_ws, size_t ws_size,
                              hipStream_t stream) {
  const float* in = (const float*)d_in[0];
  const float* Wg = (const float*)d_in[1];
  const float* bg = (const float*)d_in[2];
  float* out      = (float*)d_out;
  (void)in_sizes; (void)n_in; (void)out_size; (void)d_ws; (void)ws_size;
  qrnn3d_mfma2<<<dim3(512), dim3(256), 0, stream>>>(in, Wg, bg, out);
}

// Round 4
// 129.045 us; speedup vs baseline: 1.1663x; 1.1663x over previous
//
#include <hip/hip_runtime.h>
#include <cstdint>
#include <cstddef>

#define CIN     16
#define CHID    16
#define T_DIM   31
#define HW_     16384            // 128*128
#define CH_STRIDE 507904         // 31*128*128
#define TILE_H  4
#define TILE_W  32
#define SH      6                // TILE_H + 2
#define SW      34               // TILE_W + 2
#define SPOS    (SH * SW)        // 204 positions
#define PSTR    24               // padded shorts per position (48B: bank-stride 12 -> 2-way, free)
#define SLICE_SH (SPOS * PSTR)   // 4896 shorts = 9792 B per slice

typedef short bf16x8 __attribute__((ext_vector_type(8)));
typedef float f32x16 __attribute__((ext_vector_type(16)));

__device__ __forceinline__ unsigned bf16_bits(float x) {
  unsigned u = __builtin_bit_cast(unsigned, x);
  u += 0x7FFFu + ((u >> 16) & 1u);
  return u >> 16;
}

__device__ __forceinline__ unsigned cvt_pk_bf16(float lo, float hi) {
  unsigned r;
  asm("v_cvt_pk_bf16_f32 %0, %1, %2" : "=v"(r) : "v"(lo), "v"(hi));
  return r;
}

__global__ __launch_bounds__(256, 2)
void qrnn3d_v4(const float* __restrict__ in, const float* __restrict__ Wg,
               const float* __restrict__ bg, float* __restrict__ out) {
  __shared__ short xs[4][SLICE_SH];   // 39,168 B

  const int tid  = threadIdx.x;
  const int bid  = blockIdx.x;
  const int b    = bid >> 7;                 // 4 batches x 128 tiles
  const int tile = bid & 127;
  const int h0   = (tile >> 2) * TILE_H;     // 32 h-tiles
  const int w0   = (tile & 3) * TILE_W;      // 4 w-tiles

  const int lane = tid & 63;
  const int wid  = tid >> 6;                 // wave 0..3 -> output row
  const int col  = lane & 31;                // MFMA N column / oc for A-frag
  const int half = lane >> 5;                // K half (ci 0-7 / 8-15)

  // ---- weights -> 27 A-frags (held in unified VGPR/AGPR file) ----
  bf16x8 wfrag[27];
#pragma unroll
  for (int tau = 0; tau < 27; ++tau) {
    bf16x8 f;
#pragma unroll
    for (int j = 0; j < 8; ++j)
      f[j] = (short)bf16_bits(Wg[col * 432 + (half * 8 + j) * 27 + tau]);
    wfrag[tau] = f;
  }

  // ---- bias-preloaded accumulator template + t-invariant store offsets ----
  f32x16 accInit;
  int voff[8];
#pragma unroll
  for (int r = 0; r < 8; ++r) {
    int oc = (r & 3) + 8 * (r >> 2) + 4 * half;          // 0..15
    accInit[r]     = bg[oc];
    accInit[r + 8] = bg[oc + 16];
    voff[r] = (b * CHID + oc) * CH_STRIDE + (h0 + wid) * 128 + (w0 + col);
  }

  // ---- staging precompute (t-invariant): unit = (pos, ci-quad) ----
  const float* gp[4];
  int  lso[4];
  bool stv[4], ldv[4];
#pragma unroll
  for (int i = 0; i < 4; ++i) {
    int p   = tid + i * 256;         // [0,1024)
    int q   = p & 15;
    int c4  = (p >> 4) & 3;
    int j   = p >> 6;
    int pos = j * 16 + q;            // [0,256)
    stv[i]  = (pos < SPOS);
    int hh  = pos / SW;
    int ww  = pos - hh * SW;
    int gh  = h0 + hh - 1, gw = w0 + ww - 1;
    ldv[i]  = stv[i] && ((unsigned)gh < 128u) && ((unsigned)gw < 128u);
    int sp  = ldv[i] ? (gh * 128 + gw) : 0;
    gp[i]   = in + (size_t)(b * CIN + c4 * 4) * CH_STRIDE + sp;
    lso[i]  = pos * PSTR + c4 * 4;   // shorts
  }

#define LOADV(tz, vv)                                                \
  do {                                                               \
    if ((tz) <= 30) {                                                \
      const int toff = (tz) * HW_;                                   \
      _Pragma("unroll")                                              \
      for (int i = 0; i < 4; ++i) {                                  \
        _Pragma("unroll")                                            \
        for (int k = 0; k < 4; ++k)                                  \
          vv[i][k] = ldv[i] ? gp[i][toff + k * CH_STRIDE] : 0.0f;    \
      }                                                              \
    } else {                                                         \
      _Pragma("unroll")                                              \
      for (int i = 0; i < 4; ++i) {                                  \
        _Pragma("unroll")                                            \
        for (int k = 0; k < 4; ++k) vv[i][k] = 0.0f;                 \
      }                                                              \
    }                                                                \
  } while (0)

#define STOREV(vv, slot)                                             \
  do {                                                               \
    short* dst = &xs[(slot)][0];                                     \
    _Pragma("unroll")                                                \
    for (int i = 0; i < 4; ++i) {                                    \
      if (stv[i]) {                                                  \
        uint2 u;                                                     \
        u.x = cvt_pk_bf16(vv[i][0], vv[i][1]);                       \
        u.y = cvt_pk_bf16(vv[i][2], vv[i][3]);                       \
        *reinterpret_cast<uint2*>(dst + lso[i]) = u;                 \
      }                                                              \
    }                                                                \
  } while (0)

  // ---- compute geometry: 9 LDS read offsets (kh,kw), t-invariant ----
  int lb[9];
#pragma unroll
  for (int kh = 0; kh < 3; ++kh)
#pragma unroll
    for (int kw = 0; kw < 3; ++kw)
      lb[kh * 3 + kw] = ((wid + kh) * SW + (col + kw)) * PSTR + half * 8;

  float hst[8];
#pragma unroll
  for (int r = 0; r < 8; ++r) hst[r] = 0.0f;

  const float C_TANH = 2.8853900817779268f;   // 2*log2(e)
  const float C_SIG  = 1.4426950408889634f;   // log2(e)

  auto compute = [&](int t) {
    const short* base = &xs[0][0];
    const short* sA = base + ((t + 3) & 3) * SLICE_SH;   // slice t-1
    const short* sB = base + ((t    ) & 3) * SLICE_SH;   // slice t
    const short* sC = base + ((t + 1) & 3) * SLICE_SH;   // slice t+1

    f32x16 acc0 = accInit;
    f32x16 acc1;
#pragma unroll
    for (int i = 0; i < 16; ++i) acc1[i] = 0.0f;

#pragma unroll
    for (int kd = 0; kd < 3; ++kd) {
      const short* sp = (kd == 0) ? sA : (kd == 1) ? sB : sC;
#pragma unroll
      for (int u = 0; u < 9; ++u) {
        const int tau = kd * 9 + u;
        bf16x8 xb = *reinterpret_cast<const bf16x8*>(sp + lb[u]);
        if (tau & 1)
          acc1 = __builtin_amdgcn_mfma_f32_32x32x16_bf16(wfrag[tau], xb, acc1, 0, 0, 0);
        else
          acc0 = __builtin_amdgcn_mfma_f32_32x32x16_bf16(wfrag[tau], xb, acc0, 0, 0, 0);
      }
    }

    float* outT = out + (size_t)t * HW_;
#pragma unroll
    for (int r = 0; r < 8; ++r) {
      float zg = acc0[r] + acc1[r];
      float fg = acc0[r + 8] + acc1[r + 8];
      float ez = exp2f(zg * C_TANH);
      float z  = __builtin_fmaf(-2.0f, __builtin_amdgcn_rcpf(ez + 1.0f), 1.0f);
      float ef = exp2f(-fg * C_SIG);
      float f  = __builtin_amdgcn_rcpf(1.0f + ef);
      float h  = __builtin_fmaf(f, hst[r] - z, z);
      hst[r]   = h;
      outT[voff[r]] = h;
    }
  };

  // ---- prologue: slices 0,1 staged; slice 2 in regs; slot3 = zeros (slice -1)
  float vA[4][4], vB[4][4];
  LOADV(0, vA); STOREV(vA, 0);
  LOADV(1, vA); STOREV(vA, 1);
  LOADV(2, vA);
  for (int i = tid; i < SLICE_SH / 2; i += 256)
    reinterpret_cast<unsigned*>(&xs[3][0])[i] = 0u;
  __syncthreads();

#pragma unroll 1
  for (int t = 0; t < 30; t += 2) {
    // even step: regs A hold slice t+2
    LOADV(t + 3, vB);                 // issue loads early (hide under everything)
    STOREV(vA, (t + 2) & 3);
    compute(t);
    __syncthreads();
    // odd step: regs B hold slice t+3
    LOADV(t + 4, vA);
    STOREV(vB, (t + 3) & 3);
    compute(t + 1);
    __syncthreads();
  }
  compute(30);

#undef LOADV
#undef STOREV
}

extern "C" void kernel_launch(void* const* d_in, const int* in_sizes, int n_in,
                              void* d_out, int out_size, void* d_ws, size_t ws_size,
                              hipStream_t stream) {
  const float* in = (const float*)d_in[0];
  const float* Wg = (const float*)d_in[1];
  const float* bg = (const float*)d_in[2];
  float* out      = (float*)d_out;
  (void)in_sizes; (void)n_in; (void)out_size; (void)d_ws; (void)ws_size;
  qrnn3d_v4<<<dim3(512), dim3(256), 0, stream>>>(in, Wg, bg, out);
}